// Round 3
// baseline (196.837 us; speedup 1.0000x reference)
//
#include <hip/hip_runtime.h>
#include <stdint.h>

typedef unsigned short u16;
typedef __bf16 bfx8 __attribute__((ext_vector_type(8)));
typedef float f32x4 __attribute__((ext_vector_type(4)));

__device__ __forceinline__ u16 f2bf(float x) {
    unsigned int u = __float_as_uint(x);
    u += 0x7fffu + ((u >> 16) & 1u);
    return (u16)(u >> 16);
}

__device__ __forceinline__ void async16(const void* g, void* l) {
    __builtin_amdgcn_global_load_lds(
        (const __attribute__((address_space(1))) unsigned int*)(uintptr_t)g,
        (__attribute__((address_space(3))) unsigned int*)(unsigned int)(uintptr_t)l,
        16, 0, 0);
}

#define S_BARRIER() asm volatile("s_barrier" ::: "memory")
#define WAIT_VM6() asm volatile("s_waitcnt vmcnt(6)" ::: "memory")
#define WAIT_VM8() asm volatile("s_waitcnt vmcnt(8)" ::: "memory")
#define WAIT_VM0() asm volatile("s_waitcnt vmcnt(0)" ::: "memory")

// ---------------------------------------------------------------------------
// fused cast: 7 segments of f32 -> bf16, 8 elems/thread, one launch
// ---------------------------------------------------------------------------
struct CastArgs {
    const float* src[7];
    u16* dst[7];
    int nblk[7];
};
__global__ __launch_bounds__(256) void cast_all(CastArgs a) {
    int b = blockIdx.x, seg = 0;
    while (b >= a.nblk[seg]) { b -= a.nblk[seg]; ++seg; }
    int i = b * 256 + threadIdx.x;
    const float4* p = (const float4*)(a.src[seg] + (size_t)i * 8);
    float4 x = p[0], y = p[1];
    ushort4 o0, o1;
    o0.x = f2bf(x.x); o0.y = f2bf(x.y); o0.z = f2bf(x.z); o0.w = f2bf(x.w);
    o1.x = f2bf(y.x); o1.y = f2bf(y.y); o1.z = f2bf(y.z); o1.w = f2bf(y.w);
    ushort4* q = (ushort4*)(a.dst[seg] + (size_t)i * 8);
    q[0] = o0; q[1] = o1;
}

// ---------------------------------------------------------------------------
// NEW: 256x256 fine-phase QKV GEMM. C[M,3072] = A[M,K] * Bw[3072,K]^T.
// 8 waves (2M x 4N), wave tile 128x64, BK=64.
// LDS = 2 dbuf x {A_k0,A_k1,B_k0,B_k1} slots of 16KB = 128KB.
// 4 phases/K-tile: (ks,q) = (0,0),(0,1),(1,0),(1,1); each phase:
//   {ds_reads, stage 1 slot, s_barrier, setprio+16 MFMA, s_barrier};
//   vmcnt(8) before ending barrier of phases 2 and 4 only.
// Staging schedule (race-free; slot last-read always before stage issue):
//   P1(t): A_k1(t+1)  P2(t): B_k1(t+1)  P3(t): A_k0(t+2)  P4(t): B_k0(t+2)
// LDS chunk rotation phys = (chunk + (row>>2)) & 3, pre-rotated global src.
// Epilogue: cols 0-1023 -> Q rows, 1024-2047 -> K rows, 2048-3071 -> V^T.
// ---------------------------------------------------------------------------
#define QKV_LDA(SLOT, RBASE)                                                  \
    {                                                                         \
        _Pragma("unroll") for (int m = 0; m < 4; ++m) {                       \
            int r = (RBASE) + m * 16 + laneR;                                 \
            int ph = (laneK + (r >> 2)) & 3;                                  \
            af[m] = *(const bfx8*)(lds + (SLOT) + r * 64 + ph * 16);          \
        }                                                                     \
    }
#define QKV_LDB(SLOT)                                                         \
    {                                                                         \
        _Pragma("unroll") for (int n = 0; n < 4; ++n) {                       \
            int r = bBase + n * 16 + laneR;                                   \
            int ph = (laneK + (r >> 2)) & 3;                                  \
            bf[n] = *(const bfx8*)(lds + (SLOT) + r * 64 + ph * 16);          \
        }                                                                     \
    }
#define QKV_MFMA(Q)                                                           \
    __builtin_amdgcn_s_setprio(1);                                            \
    _Pragma("unroll") for (int m = 0; m < 4; ++m)                             \
        _Pragma("unroll") for (int n = 0; n < 4; ++n)                         \
            acc[(Q) + m][n] = __builtin_amdgcn_mfma_f32_16x16x32_bf16(        \
                af[m], bf[n], acc[(Q) + m][n], 0, 0, 0);                      \
    __builtin_amdgcn_s_setprio(0);

__global__ __launch_bounds__(512, 2)
void gemm_qkv(const u16* __restrict__ A, const u16* __restrict__ Bw,
              u16* __restrict__ outq, u16* __restrict__ outk,
              u16* __restrict__ vt, int K) {
    __shared__ __align__(1024) unsigned char lds[131072];
    const int t = threadIdx.x;
    const int lane = t & 63;
    const int w = t >> 6;
    const int laneR = lane & 15, laneK = lane >> 4;
    const int wm = w >> 2, wn = w & 3;
    // bijective XCD swizzle: 384 blocks, 48/XCD
    const int b = blockIdx.x;
    const int swz = (b & 7) * 48 + (b >> 3);
    const int row0 = (swz / 12) * 256;
    const int col0 = (swz % 12) * 256;
    const int nt = K >> 6;

    // staging precompute: dest chunk c -> row c>>2, phys chunk c&3,
    // logical chunk = (phys - (row>>2)) & 3
    const int c0 = t, c1 = 512 + t;
    const u16* pA0 = A + (size_t)(row0 + (c0 >> 2)) * K + (((c0 & 3) - (c0 >> 4)) & 3) * 8;
    const u16* pA1 = A + (size_t)(row0 + (c1 >> 2)) * K + (((c1 & 3) - (c1 >> 4)) & 3) * 8;
    const u16* pB0 = Bw + (size_t)(col0 + (c0 >> 2)) * K + (((c0 & 3) - (c0 >> 4)) & 3) * 8;
    const u16* pB1 = Bw + (size_t)(col0 + (c1 >> 2)) * K + (((c1 & 3) - (c1 >> 4)) & 3) * 8;
    const unsigned dst0 = (unsigned)c0 * 16u, dst1 = (unsigned)c1 * 16u;

    auto stageA = [&](int d, int ks, int tk) {
        unsigned base = (unsigned)d * 65536u + (unsigned)ks * 16384u;
        async16(pA0 + tk * 64 + ks * 32, lds + base + dst0);
        async16(pA1 + tk * 64 + ks * 32, lds + base + dst1);
    };
    auto stageB = [&](int d, int ks, int tk) {
        unsigned base = (unsigned)d * 65536u + 32768u + (unsigned)ks * 16384u;
        async16(pB0 + tk * 64 + ks * 32, lds + base + dst0);
        async16(pB1 + tk * 64 + ks * 32, lds + base + dst1);
    };

    // prologue: Ak0(0) Bk0(0) Ak1(0) Bk1(0) Ak0(1) Bk0(1)  (6 events, 12 loads)
    stageA(0, 0, 0); stageB(0, 0, 0);
    stageA(0, 1, 0); stageB(0, 1, 0);
    stageA(1, 0, 1); stageB(1, 0, 1);
    WAIT_VM8();       // Ak0(0),Bk0(0) landed; 4 newest events may fly
    S_BARRIER();

    f32x4 acc[8][4] = {};
    const int aRow = wm * 128;
    const int bBase = wn * 64;

    for (int tk = 0; tk < nt; ++tk) {
        const unsigned d = (unsigned)(tk & 1) * 65536u;
        const int t1 = (tk + 1 < nt) ? tk + 1 : nt - 1;  // clamp: re-stages identical bytes
        const int t2 = (tk + 2 < nt) ? tk + 2 : nt - 1;
        bfx8 af[4], bf[4];
        // ---- P1: ks=0, M-half 0 ----
        QKV_LDA(d, aRow)
        QKV_LDB(d + 32768u)
        stageA(t1 & 1, 1, t1);
        S_BARRIER();
        QKV_MFMA(0)
        S_BARRIER();
        // ---- P2: ks=0, M-half 1 (B reused in regs) ----
        QKV_LDA(d, aRow + 64)
        stageB(t1 & 1, 1, t1);
        S_BARRIER();
        QKV_MFMA(4)
        WAIT_VM8();   // Ak1(t),Bk1(t) landed (staged 4 events back)
        S_BARRIER();
        // ---- P3: ks=1, M-half 0 ----
        QKV_LDA(d + 16384u, aRow)
        QKV_LDB(d + 49152u)
        stageA(t2 & 1, 0, t2);
        S_BARRIER();
        QKV_MFMA(0)
        S_BARRIER();
        // ---- P4: ks=1, M-half 1 ----
        QKV_LDA(d + 16384u, aRow + 64)
        stageB(t2 & 1, 0, t2);
        S_BARRIER();
        QKV_MFMA(4)
        WAIT_VM8();   // Ak0(t+1),Bk0(t+1) landed
        S_BARRIER();
    }
    WAIT_VM0();       // drain before epilogue/end

    const int colsec = col0 >> 10;   // 0=Q, 1=K, 2=V
#pragma unroll
    for (int mi = 0; mi < 8; ++mi) {
        const int gr0 = row0 + wm * 128 + mi * 16 + laneK * 4;
#pragma unroll
        for (int n = 0; n < 4; ++n) {
            const int gc = col0 + wn * 64 + n * 16 + laneR;
            if (colsec == 0) {
#pragma unroll
                for (int r = 0; r < 4; ++r)
                    outq[(size_t)(gr0 + r) * 1024 + gc] = f2bf(acc[mi][n][r]);
            } else if (colsec == 1) {
#pragma unroll
                for (int r = 0; r < 4; ++r)
                    outk[(size_t)(gr0 + r) * 1024 + (gc - 1024)] = f2bf(acc[mi][n][r]);
            } else {
                ushort4 o4;
                o4.x = f2bf(acc[mi][n][0]); o4.y = f2bf(acc[mi][n][1]);
                o4.z = f2bf(acc[mi][n][2]); o4.w = f2bf(acc[mi][n][3]);
                *(ushort4*)(vt + (((size_t)(gr0 >> 12)) * 1024 + (gc - 2048)) * 4096 +
                            (gr0 & 4095)) = o4;
            }
        }
    }
}

// ---------------------------------------------------------------------------
// NT GEMM (round-2 structure): C[M,N] = A[M,K] * Bw[N,K]^T  (bf16 in, f32 acc)
// BM=256, BN=128, BK=64, 512 threads = 8 waves (4M x 2N), wave tile 64x64.
// 3-deep LDS ring, depth-2 prefetch, counted vmcnt(6), raw s_barrier.
// EPI 1: outf = res + C;  EPI 2: outb = bf16(gelu(C + bias));
// EPI 3: outf = res + C + bias
// ---------------------------------------------------------------------------
template <int EPI>
__global__ __launch_bounds__(512, 2)
void gemm_nt(const u16* __restrict__ A, const u16* __restrict__ Bw,
             u16* __restrict__ outb, float* __restrict__ outf,
             const float* __restrict__ res, const float* __restrict__ bias,
             int M, int N, int K) {
    __shared__ __align__(1024) unsigned char lds[147456];
    const int t = threadIdx.x;
    const int lane = t & 63, w = t >> 6;
    const int laneR = lane & 15, laneK = lane >> 4;
    const int wr = w >> 1, wc = w & 1;
    const int row0 = blockIdx.y * 256, col0 = blockIdx.x * 128;
    const int nt = K >> 6;

    f32x4 acc[4][4] = {};

    const u16* srcA[4];
    const u16* srcB[2];
    unsigned dA[4], dB[2];
#pragma unroll
    for (int i = 0; i < 4; ++i) {
        int li = i * 512 + t;
        int row = li >> 3, ko = li & 7;
        srcA[i] = A + (size_t)(row0 + row) * K + (ko ^ (row & 7)) * 8;
        dA[i] = li * 16;
    }
#pragma unroll
    for (int i = 0; i < 2; ++i) {
        int li = i * 512 + t;
        int row = li >> 3, ko = li & 7;
        srcB[i] = Bw + (size_t)(col0 + row) * K + (ko ^ (row & 7)) * 8;
        dB[i] = 32768 + li * 16;
    }

    auto stage = [&](int b, int tk, int h) {
        unsigned char* base = lds + b * 49152;
        const int o = tk * 64;
        if (h == 0) {
            async16(srcA[0] + o, base + dA[0]);
            async16(srcA[1] + o, base + dA[1]);
            async16(srcB[0] + o, base + dB[0]);
        } else {
            async16(srcA[2] + o, base + dA[2]);
            async16(srcA[3] + o, base + dA[3]);
            async16(srcB[1] + o, base + dB[1]);
        }
    };

    stage(0, 0, 0); stage(0, 0, 1);
    stage(1, 1, 0); stage(1, 1, 1);

    for (int tk = 0; tk < nt; ++tk) {
        unsigned char* bufA = lds + (tk % 3) * 49152;
        unsigned char* bufB = bufA + 32768;
        if (tk + 1 < nt) { WAIT_VM6(); } else { WAIT_VM0(); }
        S_BARRIER();
        const bool pf = (tk + 2 < nt);
        const int nb = (tk + 2) % 3;
#pragma unroll
        for (int ks = 0; ks < 2; ++ks) {
            bfx8 af[4], bf[4];
#pragma unroll
            for (int m = 0; m < 4; ++m) {
                int r = wr * 64 + m * 16 + laneR;
                int phys = (ks * 4 + laneK) ^ (r & 7);
                af[m] = *(const bfx8*)(bufA + r * 128 + phys * 16);
            }
#pragma unroll
            for (int n = 0; n < 4; ++n) {
                int r = wc * 64 + n * 16 + laneR;
                int phys = (ks * 4 + laneK) ^ (r & 7);
                bf[n] = *(const bfx8*)(bufB + r * 128 + phys * 16);
            }
            if (pf) stage(nb, tk + 2, ks);
            S_BARRIER();
            __builtin_amdgcn_s_setprio(1);
#pragma unroll
            for (int m = 0; m < 4; ++m)
#pragma unroll
                for (int n = 0; n < 4; ++n)
                    acc[m][n] = __builtin_amdgcn_mfma_f32_16x16x32_bf16(
                        af[m], bf[n], acc[m][n], 0, 0, 0);
            __builtin_amdgcn_s_setprio(0);
            S_BARRIER();
        }
    }

#pragma unroll
    for (int m = 0; m < 4; ++m) {
        const int gr0 = row0 + wr * 64 + m * 16 + laneK * 4;
#pragma unroll
        for (int n = 0; n < 4; ++n) {
            const int gc = col0 + wc * 64 + n * 16 + laneR;
            if constexpr (EPI == 1) {
#pragma unroll
                for (int r = 0; r < 4; ++r) {
                    size_t idx = (size_t)(gr0 + r) * N + gc;
                    outf[idx] = res[idx] + acc[m][n][r];
                }
            } else if constexpr (EPI == 2) {
#pragma unroll
                for (int r = 0; r < 4; ++r) {
                    float xx = acc[m][n][r] + bias[gc];
                    outb[(size_t)(gr0 + r) * N + gc] =
                        f2bf(xx * 0.5f * (1.0f + erff(xx * 0.70710678118654752f)));
                }
            } else {
#pragma unroll
                for (int r = 0; r < 4; ++r) {
                    size_t idx = (size_t)(gr0 + r) * N + gc;
                    outf[idx] = res[idx] + acc[m][n][r] + bias[gc];
                }
            }
        }
    }
}

// ---------------------------------------------------------------------------
// banded attention: WINDOW=32, 32-query tiles, 64-key band [i0-32, i0+31]
// ---------------------------------------------------------------------------
__global__ __launch_bounds__(256, 2)
void attn_kernel(const u16* __restrict__ Q, const u16* __restrict__ K,
                 const u16* __restrict__ vt, u16* __restrict__ O) {
    constexpr int H = 1024, S = 4096;
    const int t = threadIdx.x, lane = t & 63, w = t >> 6;
    const int laneR = lane & 15, laneK = lane >> 4;
    const int tile = blockIdx.x;
    const int batch = tile >> 7;
    const int i0 = (tile & 127) * 32;
    const size_t base = (size_t)batch * S * H;

    __shared__ __align__(16) float S4[4][32][64];
    __shared__ __align__(16) u16 P[32][72];

    f32x4 sc[2][4] = {};
    for (int h = w * 256; h < w * 256 + 256; h += 32) {
        bfx8 qa[2];
#pragma unroll
        for (int m = 0; m < 2; ++m) {
            size_t row = (size_t)(i0 + m * 16 + laneR);
            qa[m] = *(const bfx8*)(Q + base + row * H + h + laneK * 8);
        }
        bfx8 kb[4];
#pragma unroll
        for (int n = 0; n < 4; ++n) {
            int j = i0 - 32 + n * 16 + laneR;
            int jc = j < 0 ? 0 : j;
            kb[n] = *(const bfx8*)(K + base + (size_t)jc * H + h + laneK * 8);
        }
#pragma unroll
        for (int m = 0; m < 2; ++m)
#pragma unroll
            for (int n = 0; n < 4; ++n)
                sc[m][n] = __builtin_amdgcn_mfma_f32_16x16x32_bf16(
                    qa[m], kb[n], sc[m][n], 0, 0, 0);
    }
#pragma unroll
    for (int m = 0; m < 2; ++m)
#pragma unroll
        for (int n = 0; n < 4; ++n)
#pragma unroll
            for (int r = 0; r < 4; ++r)
                S4[w][m * 16 + laneK * 4 + r][n * 16 + laneR] = sc[m][n][r];
    __syncthreads();

    {
        int q = t >> 3;
        int c0 = (t & 7) * 8;
        int lo = q + 1;
        if (32 - i0 > lo) lo = 32 - i0;
        int hi = q + 32;
        float vals[8];
        float mx = -1e30f;
#pragma unroll
        for (int c = 0; c < 8; ++c) {
            int cc = c0 + c;
            float v = (S4[0][q][cc] + S4[1][q][cc] + S4[2][q][cc] + S4[3][q][cc]) * 0.03125f;
            bool valid = (cc >= lo) && (cc <= hi);
            vals[c] = valid ? v : -1e30f;
            if (vals[c] > mx) mx = vals[c];
        }
#pragma unroll
        for (int d = 1; d < 8; d <<= 1) {
            float o = __shfl_xor(mx, d);
            if (o > mx) mx = o;
        }
        float sum = 0.f;
        float es[8];
#pragma unroll
        for (int c = 0; c < 8; ++c) {
            es[c] = (vals[c] > -1e29f) ? __expf(vals[c] - mx) : 0.f;
            sum += es[c];
        }
#pragma unroll
        for (int d = 1; d < 8; d <<= 1) sum += __shfl_xor(sum, d);
        float inv = 1.0f / sum;
#pragma unroll
        for (int c = 0; c < 8; ++c) P[q][c0 + c] = f2bf(es[c] * inv);
    }
    __syncthreads();

    for (int nc = 0; nc < 4; ++nc) {
        int ncol = w * 256 + nc * 64;
        f32x4 o[2][4] = {};
#pragma unroll
        for (int ks = 0; ks < 2; ++ks) {
            bfx8 pa[2];
#pragma unroll
            for (int m = 0; m < 2; ++m)
                pa[m] = *(const bfx8*)(&P[m * 16 + laneR][ks * 32 + laneK * 8]);
            int t0 = i0 - 32 + ks * 32 + laneK * 8;
            if (t0 < 0) t0 = 0;
#pragma unroll
            for (int n = 0; n < 4; ++n) {
                int c = ncol + n * 16 + laneR;
                bfx8 vb = *(const bfx8*)(vt + ((size_t)batch * 1024 + c) * 4096 + t0);
#pragma unroll
                for (int m = 0; m < 2; ++m)
                    o[m][n] = __builtin_amdgcn_mfma_f32_16x16x32_bf16(
                        pa[m], vb, o[m][n], 0, 0, 0);
            }
        }
#pragma unroll
        for (int m = 0; m < 2; ++m)
#pragma unroll
            for (int n = 0; n < 4; ++n)
#pragma unroll
                for (int r = 0; r < 4; ++r) {
                    size_t row = (size_t)(i0 + m * 16 + laneK * 4 + r);
                    O[base + row * H + ncol + n * 16 + laneR] = f2bf(o[m][n][r]);
                }
    }
}

// ---------------------------------------------------------------------------
// LayerNorm over H=1024, one block per row, f32 in -> bf16 out
// ---------------------------------------------------------------------------
__global__ __launch_bounds__(256)
void ln_kernel(const float* __restrict__ x, const float* __restrict__ gw,
               const float* __restrict__ gb, u16* __restrict__ out) {
    const int row = blockIdx.x, t = threadIdx.x;
    const float4 v = ((const float4*)(x + (size_t)row * 1024))[t];
    float s = v.x + v.y + v.z + v.w;
    float s2 = v.x * v.x + v.y * v.y + v.z * v.z + v.w * v.w;
#pragma unroll
    for (int d = 1; d < 64; d <<= 1) {
        s += __shfl_xor(s, d);
        s2 += __shfl_xor(s2, d);
    }
    __shared__ float red[8];
    int lane = t & 63, wv = t >> 6;
    if (lane == 0) { red[wv] = s; red[4 + wv] = s2; }
    __syncthreads();
    float S1 = red[0] + red[1] + red[2] + red[3];
    float S2 = red[4] + red[5] + red[6] + red[7];
    float mu = S1 * (1.0f / 1024.0f);
    float var = S2 * (1.0f / 1024.0f) - mu * mu;
    float rstd = rsqrtf(var + 1e-5f);
    const float4 wv4 = ((const float4*)gw)[t];
    const float4 bv4 = ((const float4*)gb)[t];
    ushort4 o;
    o.x = f2bf((v.x - mu) * rstd * wv4.x + bv4.x);
    o.y = f2bf((v.y - mu) * rstd * wv4.y + bv4.y);
    o.z = f2bf((v.z - mu) * rstd * wv4.z + bv4.z);
    o.w = f2bf((v.w - mu) * rstd * wv4.w + bv4.w);
    ((ushort4*)(out + (size_t)row * 1024))[t] = o;
}

// ---------------------------------------------------------------------------
extern "C" void kernel_launch(void* const* d_in, const int* in_sizes, int n_in,
                              void* d_out, int out_size, void* d_ws, size_t ws_size,
                              hipStream_t stream) {
    const float* x   = (const float*)d_in[0];
    const float* Wq  = (const float*)d_in[1];
    const float* Wk  = (const float*)d_in[2];
    const float* Wv  = (const float*)d_in[3];
    const float* Wo  = (const float*)d_in[4];
    const float* lnw = (const float*)d_in[5];
    const float* lnb = (const float*)d_in[6];
    const float* W1  = (const float*)d_in[7];
    const float* b1  = (const float*)d_in[8];
    const float* W2  = (const float*)d_in[9];
    const float* b2  = (const float*)d_in[10];
    (void)in_sizes; (void)n_in; (void)out_size; (void)ws_size;

    const int M = 8192, H = 1024, Hh = 512;

    char* ws = (char*)d_ws;
    size_t off = 0;
    auto alloc = [&](size_t bytes) {
        char* p = ws + off;
        off += (bytes + 255) & ~(size_t)255;
        return p;
    };
    u16* Xb    = (u16*)alloc((size_t)M * H * 2);      // reused as Attb after QKV
    u16* Wqkvb = (u16*)alloc((size_t)3 * H * H * 2);  // [3072][1024]
    u16* Wob   = (u16*)alloc((size_t)H * H * 2);
    u16* W1b   = (u16*)alloc((size_t)Hh * H * 2);
    u16* W2b   = (u16*)alloc((size_t)H * Hh * 2);
    u16* Qb    = (u16*)alloc((size_t)M * H * 2);      // reused as hlnb after attn
    u16* Kb    = (u16*)alloc((size_t)M * H * 2);      // reused as Gb after attn
    u16* Vt    = (u16*)alloc((size_t)M * H * 2);      // [2][1024][4096] V^T
    float* draft = (float*)alloc((size_t)M * H * 4);
    u16* Attb = Xb;
    u16* hlnb = Qb;
    u16* Gb   = Kb;
    float* outp = (float*)d_out;

    CastArgs ca;
    ca.src[0] = x;  ca.dst[0] = Xb;                        ca.nblk[0] = (M * H / 8) / 256;
    ca.src[1] = Wq; ca.dst[1] = Wqkvb;                     ca.nblk[1] = (H * H / 8) / 256;
    ca.src[2] = Wk; ca.dst[2] = Wqkvb + (size_t)H * H;     ca.nblk[2] = (H * H / 8) / 256;
    ca.src[3] = Wv; ca.dst[3] = Wqkvb + (size_t)2 * H * H; ca.nblk[3] = (H * H / 8) / 256;
    ca.src[4] = Wo; ca.dst[4] = Wob;                       ca.nblk[4] = (H * H / 8) / 256;
    ca.src[5] = W1; ca.dst[5] = W1b;                       ca.nblk[5] = (Hh * H / 8) / 256;
    ca.src[6] = W2; ca.dst[6] = W2b;                       ca.nblk[6] = (H * Hh / 8) / 256;
    int totblk = 0;
    for (int i = 0; i < 7; ++i) totblk += ca.nblk[i];
    cast_all<<<dim3(totblk), dim3(256), 0, stream>>>(ca);

    // fused QKV GEMM (new 256^2 fine-phase kernel), 384 blocks
    gemm_qkv<<<dim3(384), dim3(512), 0, stream>>>(Xb, Wqkvb, Qb, Kb, Vt, H);

    attn_kernel<<<dim3(256), dim3(256), 0, stream>>>(Qb, Kb, Vt, Attb);

    gemm_nt<1><<<dim3(H / 128, M / 256), dim3(512), 0, stream>>>(
        Attb, Wob, nullptr, draft, x, nullptr, M, H, H);

    ln_kernel<<<dim3(M), dim3(256), 0, stream>>>(draft, lnw, lnb, hlnb);

    gemm_nt<2><<<dim3(Hh / 128, M / 256), dim3(512), 0, stream>>>(
        hlnb, W1b, Gb, nullptr, nullptr, b1, M, Hh, H);

    gemm_nt<3><<<dim3(H / 128, M / 256), dim3(512), 0, stream>>>(
        Gb, W2b, nullptr, outp, draft, b2, M, H, Hh);
}

// Round 4
// 192.103 us; speedup vs baseline: 1.0246x; 1.0246x over previous
//
#include <hip/hip_runtime.h>
#include <stdint.h>

typedef unsigned short u16;
typedef __bf16 bfx8 __attribute__((ext_vector_type(8)));
typedef float f32x4 __attribute__((ext_vector_type(4)));

__device__ __forceinline__ u16 f2bf(float x) {
    unsigned int u = __float_as_uint(x);
    u += 0x7fffu + ((u >> 16) & 1u);
    return (u16)(u >> 16);
}

__device__ __forceinline__ void async16(const void* g, void* l) {
    __builtin_amdgcn_global_load_lds(
        (const __attribute__((address_space(1))) unsigned int*)(uintptr_t)g,
        (__attribute__((address_space(3))) unsigned int*)(unsigned int)(uintptr_t)l,
        16, 0, 0);
}

#define S_BARRIER() asm volatile("s_barrier" ::: "memory")
#define WAIT_VM6() asm volatile("s_waitcnt vmcnt(6)" ::: "memory")
#define WAIT_VM4() asm volatile("s_waitcnt vmcnt(4)" ::: "memory")
#define WAIT_VM2() asm volatile("s_waitcnt vmcnt(2)" ::: "memory")
#define WAIT_VM0() asm volatile("s_waitcnt vmcnt(0)" ::: "memory")

// ---------------------------------------------------------------------------
// fused cast: 7 segments of f32 -> bf16, 8 elems/thread, one launch
// ---------------------------------------------------------------------------
struct CastArgs {
    const float* src[7];
    u16* dst[7];
    int nblk[7];
};
__global__ __launch_bounds__(256) void cast_all(CastArgs a) {
    int b = blockIdx.x, seg = 0;
    while (b >= a.nblk[seg]) { b -= a.nblk[seg]; ++seg; }
    int i = b * 256 + threadIdx.x;
    const float4* p = (const float4*)(a.src[seg] + (size_t)i * 8);
    float4 x = p[0], y = p[1];
    ushort4 o0, o1;
    o0.x = f2bf(x.x); o0.y = f2bf(x.y); o0.z = f2bf(x.z); o0.w = f2bf(x.w);
    o1.x = f2bf(y.x); o1.y = f2bf(y.y); o1.z = f2bf(y.z); o1.w = f2bf(y.w);
    ushort4* q = (ushort4*)(a.dst[seg] + (size_t)i * 8);
    q[0] = o0; q[1] = o1;
}

// ---------------------------------------------------------------------------
// 256x256 fine-phase QKV GEMM. C[M,3072] = A[M,K] * Bw[3072,K]^T.
// 8 waves (2M x 4N), wave tile 128x64, BK=64.
// LDS: 2 buffers x (A 32KB + B 32KB); rows of 128B x 8 chunks,
// phys chunk = ko ^ (row&7) (round-2-proven conflict-free layout),
// applied on DMA source and ds_read side.
// 4 phases/K-tile (ks, M-half); per phase {ds_reads, stage, barrier,
// setprio+16 MFMA, [vmcnt], barrier}.
// Stage units of t+1: P1 issues A-lo,B-lo; P2 issues B-hi,A-hi.
// Waits: vmcnt(4) end-P1 (drains A-hi(t)), vmcnt(2) end-P4 (drains
// A-lo/B-lo/B-hi(t+1), lets A-hi(t+1) fly). FIFO-exact per wave.
// Epilogue: cols 0-1023 -> Q, 1024-2047 -> K, 2048-3071 -> V^T.
// ---------------------------------------------------------------------------
__global__ __launch_bounds__(512, 2)
void gemm_qkv(const u16* __restrict__ A, const u16* __restrict__ Bw,
              u16* __restrict__ outq, u16* __restrict__ outk,
              u16* __restrict__ vt, int K) {
    __shared__ __align__(1024) unsigned char lds[131072];
    const int t = threadIdx.x;
    const int lane = t & 63, w = t >> 6;
    const int laneR = lane & 15, laneK = lane >> 4;
    const int wm = w >> 2, wn = w & 3;
    const int b = blockIdx.x;
    const int swz = (b & 7) * 48 + (b >> 3);   // bijective: 384 = 8 * 48
    const int row0 = (swz / 12) * 256;
    const int col0 = (swz % 12) * 256;
    const int nt = K >> 6;

    // staging: chunk c (0..2047/matrix): row=c>>3, phys ko=c&7,
    // logical ko=(c&7)^(row&7); thread t owns c = u*1024 + j*512 + t
    const u16* pA[2][2];
    const u16* pB[2][2];
#pragma unroll
    for (int u = 0; u < 2; ++u)
#pragma unroll
        for (int j = 0; j < 2; ++j) {
            int c = u * 1024 + j * 512 + t;
            int row = c >> 3;
            int ko = (c & 7) ^ (row & 7);
            pA[u][j] = A + (size_t)(row0 + row) * K + ko * 8;
            pB[u][j] = Bw + (size_t)(col0 + row) * K + ko * 8;
        }

    auto stageA = [&](unsigned d, int u, int tk) {
        async16(pA[u][0] + tk * 64, lds + d + (u * 1024 + t) * 16);
        async16(pA[u][1] + tk * 64, lds + d + (u * 1024 + 512 + t) * 16);
    };
    auto stageB = [&](unsigned d, int u, int tk) {
        async16(pB[u][0] + tk * 64, lds + d + 32768u + (u * 1024 + t) * 16);
        async16(pB[u][1] + tk * 64, lds + d + 32768u + (u * 1024 + 512 + t) * 16);
    };

    f32x4 acc[8][4] = {};
    const int aR = wm * 128;
    const int bR = wn * 64;
    bfx8 af[4], bf[4];

    auto LDA = [&](unsigned d, int ks, int half) {
#pragma unroll
        for (int m = 0; m < 4; ++m) {
            int r = aR + half * 64 + m * 16 + laneR;
            int ph = (ks * 4 + laneK) ^ (r & 7);
            af[m] = *(const bfx8*)(lds + d + r * 128 + ph * 16);
        }
    };
    auto LDB = [&](unsigned d, int ks) {
#pragma unroll
        for (int n = 0; n < 4; ++n) {
            int r = bR + n * 16 + laneR;
            int ph = (ks * 4 + laneK) ^ (r & 7);
            bf[n] = *(const bfx8*)(lds + d + 32768u + r * 128 + ph * 16);
        }
    };
    auto DOMFMA = [&](int off) {
        __builtin_amdgcn_s_setprio(1);
#pragma unroll
        for (int m = 0; m < 4; ++m)
#pragma unroll
            for (int n = 0; n < 4; ++n)
                acc[off + m][n] = __builtin_amdgcn_mfma_f32_16x16x32_bf16(
                    af[m], bf[n], acc[off + m][n], 0, 0, 0);
        __builtin_amdgcn_s_setprio(0);
    };

    // prologue: fully stage tile 0 into buffer 0 (8 events), drain once
    stageA(0, 0, 0); stageB(0, 0, 0); stageB(0, 1, 0); stageA(0, 1, 0);
    WAIT_VM0();
    S_BARRIER();

    for (int tk = 0; tk < nt; ++tk) {
        const unsigned d = (unsigned)(tk & 1) * 65536u;
        const unsigned nd = d ^ 65536u;
        const bool pf = (tk + 1 < nt);
        // ---- P1: ks=0, half=0 ----
        LDA(d, 0, 0);
        LDB(d, 0);
        if (pf) { stageA(nd, 0, tk + 1); stageB(nd, 0, tk + 1); }
        S_BARRIER();
        DOMFMA(0);
        WAIT_VM4();       // drain A-hi(t); allow A-lo/B-lo(t+1) in flight
        S_BARRIER();
        // ---- P2: ks=0, half=1 (B held in regs) ----
        LDA(d, 0, 1);
        if (pf) { stageB(nd, 1, tk + 1); stageA(nd, 1, tk + 1); }
        S_BARRIER();
        DOMFMA(4);
        S_BARRIER();
        // ---- P3: ks=1, half=0 ----
        LDA(d, 1, 0);
        LDB(d, 1);
        S_BARRIER();
        DOMFMA(0);
        S_BARRIER();
        // ---- P4: ks=1, half=1 ----
        LDA(d, 1, 1);
        S_BARRIER();
        DOMFMA(4);
        WAIT_VM2();       // drain A-lo/B-lo/B-hi(t+1); A-hi(t+1) may fly
        S_BARRIER();
    }
    WAIT_VM0();

    const int colsec = col0 >> 10;   // 0=Q, 1=K, 2=V
#pragma unroll
    for (int mi = 0; mi < 8; ++mi) {
        const int gr0 = row0 + wm * 128 + mi * 16 + laneK * 4;
#pragma unroll
        for (int n = 0; n < 4; ++n) {
            const int gc = col0 + wn * 64 + n * 16 + laneR;
            if (colsec == 0) {
#pragma unroll
                for (int r = 0; r < 4; ++r)
                    outq[(size_t)(gr0 + r) * 1024 + gc] = f2bf(acc[mi][n][r]);
            } else if (colsec == 1) {
#pragma unroll
                for (int r = 0; r < 4; ++r)
                    outk[(size_t)(gr0 + r) * 1024 + (gc - 1024)] = f2bf(acc[mi][n][r]);
            } else {
                ushort4 o4;
                o4.x = f2bf(acc[mi][n][0]); o4.y = f2bf(acc[mi][n][1]);
                o4.z = f2bf(acc[mi][n][2]); o4.w = f2bf(acc[mi][n][3]);
                *(ushort4*)(vt + (((size_t)(gr0 >> 12)) * 1024 + (gc - 2048)) * 4096 +
                            (gr0 & 4095)) = o4;
            }
        }
    }
}

// ---------------------------------------------------------------------------
// NT GEMM (round-2 structure, proven 0 conflicts): C = A * Bw^T
// BM=256, BN=128, BK=64, 8 waves (4M x 2N), wave tile 64x64.
// 3-deep LDS ring, depth-2 prefetch, counted vmcnt(6).
// EPI 1: outf = res + C;  EPI 2: outb = bf16(gelu(C + bias));
// EPI 3: outf = res + C + bias
// ---------------------------------------------------------------------------
template <int EPI>
__global__ __launch_bounds__(512, 2)
void gemm_nt(const u16* __restrict__ A, const u16* __restrict__ Bw,
             u16* __restrict__ outb, float* __restrict__ outf,
             const float* __restrict__ res, const float* __restrict__ bias,
             int M, int N, int K) {
    __shared__ __align__(1024) unsigned char lds[147456];
    const int t = threadIdx.x;
    const int lane = t & 63, w = t >> 6;
    const int laneR = lane & 15, laneK = lane >> 4;
    const int wr = w >> 1, wc = w & 1;
    const int row0 = blockIdx.y * 256, col0 = blockIdx.x * 128;
    const int nt = K >> 6;

    f32x4 acc[4][4] = {};

    const u16* srcA[4];
    const u16* srcB[2];
    unsigned dA[4], dB[2];
#pragma unroll
    for (int i = 0; i < 4; ++i) {
        int li = i * 512 + t;
        int row = li >> 3, ko = li & 7;
        srcA[i] = A + (size_t)(row0 + row) * K + (ko ^ (row & 7)) * 8;
        dA[i] = li * 16;
    }
#pragma unroll
    for (int i = 0; i < 2; ++i) {
        int li = i * 512 + t;
        int row = li >> 3, ko = li & 7;
        srcB[i] = Bw + (size_t)(col0 + row) * K + (ko ^ (row & 7)) * 8;
        dB[i] = 32768 + li * 16;
    }

    auto stage = [&](int b, int tk, int h) {
        unsigned char* base = lds + b * 49152;
        const int o = tk * 64;
        if (h == 0) {
            async16(srcA[0] + o, base + dA[0]);
            async16(srcA[1] + o, base + dA[1]);
            async16(srcB[0] + o, base + dB[0]);
        } else {
            async16(srcA[2] + o, base + dA[2]);
            async16(srcA[3] + o, base + dA[3]);
            async16(srcB[1] + o, base + dB[1]);
        }
    };

    stage(0, 0, 0); stage(0, 0, 1);
    stage(1, 1, 0); stage(1, 1, 1);

    for (int tk = 0; tk < nt; ++tk) {
        unsigned char* bufA = lds + (tk % 3) * 49152;
        unsigned char* bufB = bufA + 32768;
        if (tk + 1 < nt) { WAIT_VM6(); } else { WAIT_VM0(); }
        S_BARRIER();
        const bool pf = (tk + 2 < nt);
        const int nb = (tk + 2) % 3;
#pragma unroll
        for (int ks = 0; ks < 2; ++ks) {
            bfx8 af[4], bf[4];
#pragma unroll
            for (int m = 0; m < 4; ++m) {
                int r = wr * 64 + m * 16 + laneR;
                int phys = (ks * 4 + laneK) ^ (r & 7);
                af[m] = *(const bfx8*)(bufA + r * 128 + phys * 16);
            }
#pragma unroll
            for (int n = 0; n < 4; ++n) {
                int r = wc * 64 + n * 16 + laneR;
                int phys = (ks * 4 + laneK) ^ (r & 7);
                bf[n] = *(const bfx8*)(bufB + r * 128 + phys * 16);
            }
            if (pf) stage(nb, tk + 2, ks);
            S_BARRIER();
            __builtin_amdgcn_s_setprio(1);
#pragma unroll
            for (int m = 0; m < 4; ++m)
#pragma unroll
                for (int n = 0; n < 4; ++n)
                    acc[m][n] = __builtin_amdgcn_mfma_f32_16x16x32_bf16(
                        af[m], bf[n], acc[m][n], 0, 0, 0);
            __builtin_amdgcn_s_setprio(0);
            S_BARRIER();
        }
    }

#pragma unroll
    for (int m = 0; m < 4; ++m) {
        const int gr0 = row0 + wr * 64 + m * 16 + laneK * 4;
#pragma unroll
        for (int n = 0; n < 4; ++n) {
            const int gc = col0 + wc * 64 + n * 16 + laneR;
            if constexpr (EPI == 1) {
#pragma unroll
                for (int r = 0; r < 4; ++r) {
                    size_t idx = (size_t)(gr0 + r) * N + gc;
                    outf[idx] = res[idx] + acc[m][n][r];
                }
            } else if constexpr (EPI == 2) {
#pragma unroll
                for (int r = 0; r < 4; ++r) {
                    float xx = acc[m][n][r] + bias[gc];
                    outb[(size_t)(gr0 + r) * N + gc] =
                        f2bf(xx * 0.5f * (1.0f + erff(xx * 0.70710678118654752f)));
                }
            } else {
#pragma unroll
                for (int r = 0; r < 4; ++r) {
                    size_t idx = (size_t)(gr0 + r) * N + gc;
                    outf[idx] = res[idx] + acc[m][n][r] + bias[gc];
                }
            }
        }
    }
}

// ---------------------------------------------------------------------------
// banded attention: WINDOW=32, 32-query tiles, 64-key band [i0-32, i0+31]
// ---------------------------------------------------------------------------
__global__ __launch_bounds__(256, 2)
void attn_kernel(const u16* __restrict__ Q, const u16* __restrict__ K,
                 const u16* __restrict__ vt, u16* __restrict__ O) {
    constexpr int H = 1024, S = 4096;
    const int t = threadIdx.x, lane = t & 63, w = t >> 6;
    const int laneR = lane & 15, laneK = lane >> 4;
    const int tile = blockIdx.x;
    const int batch = tile >> 7;
    const int i0 = (tile & 127) * 32;
    const size_t base = (size_t)batch * S * H;

    __shared__ __align__(16) float S4[4][32][64];
    __shared__ __align__(16) u16 P[32][72];

    f32x4 sc[2][4] = {};
    for (int h = w * 256; h < w * 256 + 256; h += 32) {
        bfx8 qa[2];
#pragma unroll
        for (int m = 0; m < 2; ++m) {
            size_t row = (size_t)(i0 + m * 16 + laneR);
            qa[m] = *(const bfx8*)(Q + base + row * H + h + laneK * 8);
        }
        bfx8 kb[4];
#pragma unroll
        for (int n = 0; n < 4; ++n) {
            int j = i0 - 32 + n * 16 + laneR;
            int jc = j < 0 ? 0 : j;
            kb[n] = *(const bfx8*)(K + base + (size_t)jc * H + h + laneK * 8);
        }
#pragma unroll
        for (int m = 0; m < 2; ++m)
#pragma unroll
            for (int n = 0; n < 4; ++n)
                sc[m][n] = __builtin_amdgcn_mfma_f32_16x16x32_bf16(
                    qa[m], kb[n], sc[m][n], 0, 0, 0);
    }
#pragma unroll
    for (int m = 0; m < 2; ++m)
#pragma unroll
        for (int n = 0; n < 4; ++n)
#pragma unroll
            for (int r = 0; r < 4; ++r)
                S4[w][m * 16 + laneK * 4 + r][n * 16 + laneR] = sc[m][n][r];
    __syncthreads();

    {
        int q = t >> 3;
        int c0 = (t & 7) * 8;
        int lo = q + 1;
        if (32 - i0 > lo) lo = 32 - i0;
        int hi = q + 32;
        float vals[8];
        float mx = -1e30f;
#pragma unroll
        for (int c = 0; c < 8; ++c) {
            int cc = c0 + c;
            float v = (S4[0][q][cc] + S4[1][q][cc] + S4[2][q][cc] + S4[3][q][cc]) * 0.03125f;
            bool valid = (cc >= lo) && (cc <= hi);
            vals[c] = valid ? v : -1e30f;
            if (vals[c] > mx) mx = vals[c];
        }
#pragma unroll
        for (int d = 1; d < 8; d <<= 1) {
            float o = __shfl_xor(mx, d);
            if (o > mx) mx = o;
        }
        float sum = 0.f;
        float es[8];
#pragma unroll
        for (int c = 0; c < 8; ++c) {
            es[c] = (vals[c] > -1e29f) ? __expf(vals[c] - mx) : 0.f;
            sum += es[c];
        }
#pragma unroll
        for (int d = 1; d < 8; d <<= 1) sum += __shfl_xor(sum, d);
        float inv = 1.0f / sum;
#pragma unroll
        for (int c = 0; c < 8; ++c) P[q][c0 + c] = f2bf(es[c] * inv);
    }
    __syncthreads();

    for (int nc = 0; nc < 4; ++nc) {
        int ncol = w * 256 + nc * 64;
        f32x4 o[2][4] = {};
#pragma unroll
        for (int ks = 0; ks < 2; ++ks) {
            bfx8 pa[2];
#pragma unroll
            for (int m = 0; m < 2; ++m)
                pa[m] = *(const bfx8*)(&P[m * 16 + laneR][ks * 32 + laneK * 8]);
            int t0 = i0 - 32 + ks * 32 + laneK * 8;
            if (t0 < 0) t0 = 0;
#pragma unroll
            for (int n = 0; n < 4; ++n) {
                int c = ncol + n * 16 + laneR;
                bfx8 vb = *(const bfx8*)(vt + ((size_t)batch * 1024 + c) * 4096 + t0);
#pragma unroll
                for (int m = 0; m < 2; ++m)
                    o[m][n] = __builtin_amdgcn_mfma_f32_16x16x32_bf16(
                        pa[m], vb, o[m][n], 0, 0, 0);
            }
        }
#pragma unroll
        for (int m = 0; m < 2; ++m)
#pragma unroll
            for (int n = 0; n < 4; ++n)
#pragma unroll
                for (int r = 0; r < 4; ++r) {
                    size_t row = (size_t)(i0 + m * 16 + laneK * 4 + r);
                    O[base + row * H + ncol + n * 16 + laneR] = f2bf(o[m][n][r]);
                }
    }
}

// ---------------------------------------------------------------------------
// LayerNorm over H=1024, one block per row, f32 in -> bf16 out
// ---------------------------------------------------------------------------
__global__ __launch_bounds__(256)
void ln_kernel(const float* __restrict__ x, const float* __restrict__ gw,
               const float* __restrict__ gb, u16* __restrict__ out) {
    const int row = blockIdx.x, t = threadIdx.x;
    const float4 v = ((const float4*)(x + (size_t)row * 1024))[t];
    float s = v.x + v.y + v.z + v.w;
    float s2 = v.x * v.x + v.y * v.y + v.z * v.z + v.w * v.w;
#pragma unroll
    for (int d = 1; d < 64; d <<= 1) {
        s += __shfl_xor(s, d);
        s2 += __shfl_xor(s2, d);
    }
    __shared__ float red[8];
    int lane = t & 63, wv = t >> 6;
    if (lane == 0) { red[wv] = s; red[4 + wv] = s2; }
    __syncthreads();
    float S1 = red[0] + red[1] + red[2] + red[3];
    float S2 = red[4] + red[5] + red[6] + red[7];
    float mu = S1 * (1.0f / 1024.0f);
    float var = S2 * (1.0f / 1024.0f) - mu * mu;
    float rstd = rsqrtf(var + 1e-5f);
    const float4 wv4 = ((const float4*)gw)[t];
    const float4 bv4 = ((const float4*)gb)[t];
    ushort4 o;
    o.x = f2bf((v.x - mu) * rstd * wv4.x + bv4.x);
    o.y = f2bf((v.y - mu) * rstd * wv4.y + bv4.y);
    o.z = f2bf((v.z - mu) * rstd * wv4.z + bv4.z);
    o.w = f2bf((v.w - mu) * rstd * wv4.w + bv4.w);
    ((ushort4*)(out + (size_t)row * 1024))[t] = o;
}

// ---------------------------------------------------------------------------
extern "C" void kernel_launch(void* const* d_in, const int* in_sizes, int n_in,
                              void* d_out, int out_size, void* d_ws, size_t ws_size,
                              hipStream_t stream) {
    const float* x   = (const float*)d_in[0];
    const float* Wq  = (const float*)d_in[1];
    const float* Wk  = (const float*)d_in[2];
    const float* Wv  = (const float*)d_in[3];
    const float* Wo  = (const float*)d_in[4];
    const float* lnw = (const float*)d_in[5];
    const float* lnb = (const float*)d_in[6];
    const float* W1  = (const float*)d_in[7];
    const float* b1  = (const float*)d_in[8];
    const float* W2  = (const float*)d_in[9];
    const float* b2  = (const float*)d_in[10];
    (void)in_sizes; (void)n_in; (void)out_size; (void)ws_size;

    const int M = 8192, H = 1024, Hh = 512;

    char* ws = (char*)d_ws;
    size_t off = 0;
    auto alloc = [&](size_t bytes) {
        char* p = ws + off;
        off += (bytes + 255) & ~(size_t)255;
        return p;
    };
    u16* Xb    = (u16*)alloc((size_t)M * H * 2);      // reused as Attb after QKV
    u16* Wqkvb = (u16*)alloc((size_t)3 * H * H * 2);  // [3072][1024]
    u16* Wob   = (u16*)alloc((size_t)H * H * 2);
    u16* W1b   = (u16*)alloc((size_t)Hh * H * 2);
    u16* W2b   = (u16*)alloc((size_t)H * Hh * 2);
    u16* Qb    = (u16*)alloc((size_t)M * H * 2);      // reused as hlnb after attn
    u16* Kb    = (u16*)alloc((size_t)M * H * 2);      // reused as Gb after attn
    u16* Vt    = (u16*)alloc((size_t)M * H * 2);      // [2][1024][4096] V^T
    float* draft = (float*)alloc((size_t)M * H * 4);
    u16* Attb = Xb;
    u16* hlnb = Qb;
    u16* Gb   = Kb;
    float* outp = (float*)d_out;

    CastArgs ca;
    ca.src[0] = x;  ca.dst[0] = Xb;                        ca.nblk[0] = (M * H / 8) / 256;
    ca.src[1] = Wq; ca.dst[1] = Wqkvb;                     ca.nblk[1] = (H * H / 8) / 256;
    ca.src[2] = Wk; ca.dst[2] = Wqkvb + (size_t)H * H;     ca.nblk[2] = (H * H / 8) / 256;
    ca.src[3] = Wv; ca.dst[3] = Wqkvb + (size_t)2 * H * H; ca.nblk[3] = (H * H / 8) / 256;
    ca.src[4] = Wo; ca.dst[4] = Wob;                       ca.nblk[4] = (H * H / 8) / 256;
    ca.src[5] = W1; ca.dst[5] = W1b;                       ca.nblk[5] = (Hh * H / 8) / 256;
    ca.src[6] = W2; ca.dst[6] = W2b;                       ca.nblk[6] = (H * Hh / 8) / 256;
    int totblk = 0;
    for (int i = 0; i < 7; ++i) totblk += ca.nblk[i];
    cast_all<<<dim3(totblk), dim3(256), 0, stream>>>(ca);

    gemm_qkv<<<dim3(384), dim3(512), 0, stream>>>(Xb, Wqkvb, Qb, Kb, Vt, H);

    attn_kernel<<<dim3(256), dim3(256), 0, stream>>>(Qb, Kb, Vt, Attb);

    gemm_nt<1><<<dim3(H / 128, M / 256), dim3(512), 0, stream>>>(
        Attb, Wob, nullptr, draft, x, nullptr, M, H, H);

    ln_kernel<<<dim3(M), dim3(256), 0, stream>>>(draft, lnw, lnb, hlnb);

    gemm_nt<2><<<dim3(Hh / 128, M / 256), dim3(512), 0, stream>>>(
        hlnb, W1b, Gb, nullptr, nullptr, b1, M, Hh, H);

    gemm_nt<3><<<dim3(H / 128, M / 256), dim3(512), 0, stream>>>(
        Gb, W2b, nullptr, outp, draft, b2, M, H, Hh);
}